// Round 5
// baseline (376.662 us; speedup 1.0000x reference)
//
#include <hip/hip_runtime.h>
#include <hip/hip_bf16.h>

#define T_LEN 1024
#define D_DIM 64
#define BATCH 32

// ---------------------------------------------------------------------------
// Kernel 1: pairwise Euclidean distance, GEMM-trick.
// 128x128 tile, 256 threads, 8x8 micro-tile. UNCHANGED (its ~130us is tile-
// size-invariant; waiting for counters once dp drops below it).
// ---------------------------------------------------------------------------
#define BM 128
#define BN 128

__global__ __launch_bounds__(256, 2) void cost_kernel(const float* __restrict__ pred,
                                                      const float* __restrict__ targ,
                                                      float* __restrict__ cost) {
    const int b = blockIdx.z;
    const float* P = pred + (size_t)b * T_LEN * D_DIM;
    const float* Tg = targ + (size_t)b * T_LEN * D_DIM;
    float* C = cost + (size_t)b * T_LEN * T_LEN;
    const int row0 = blockIdx.y * BM;
    const int col0 = blockIdx.x * BN;

    __shared__ __align__(16) float ps[BM][D_DIM + 4];
    __shared__ __align__(16) float ts[D_DIM][BN + 4];
    __shared__ float p2[BM], t2[BN];

    const int tid = threadIdx.x;

#pragma unroll
    for (int it = 0; it < 8; ++it) {
        int f = tid + 256 * it;
        int row = f >> 4;
        int kc = f & 15;
        float4 v = *(const float4*)(P + (size_t)(row0 + row) * D_DIM + 4 * kc);
        *(float4*)&ps[row][4 * kc] = v;
    }
#pragma unroll
    for (int it = 0; it < 8; ++it) {
        int f = tid + 256 * it;
        int col = f >> 4;
        int kc = f & 15;
        float4 w = *(const float4*)(Tg + (size_t)(col0 + col) * D_DIM + 4 * kc);
        ts[4 * kc + 0][col] = w.x;
        ts[4 * kc + 1][col] = w.y;
        ts[4 * kc + 2][col] = w.z;
        ts[4 * kc + 3][col] = w.w;
    }
    __syncthreads();

    if (tid < 128) {
        float s = 0.0f;
        const float4* pr = (const float4*)&ps[tid][0];
#pragma unroll
        for (int q = 0; q < 16; ++q) {
            float4 v = pr[q];
            s += v.x * v.x; s += v.y * v.y; s += v.z * v.z; s += v.w * v.w;
        }
        p2[tid] = s;
    } else {
        int c = tid - 128;
        float s = 0.0f;
#pragma unroll
        for (int k = 0; k < 64; ++k) { float x = ts[k][c]; s += x * x; }
        t2[c] = s;
    }
    __syncthreads();

    const int tx = tid & 15;
    const int ty = tid >> 4;
    const int cl = 4 * tx;
    const int ch = 64 + 4 * tx;

    float acc[8][8];
#pragma unroll
    for (int i = 0; i < 8; ++i)
#pragma unroll
        for (int j = 0; j < 8; ++j) acc[i][j] = 0.0f;

#pragma unroll
    for (int k4 = 0; k4 < 16; ++k4) {
        float4 bl[4], bh[4];
#pragma unroll
        for (int kk = 0; kk < 4; ++kk) {
            bl[kk] = *(const float4*)&ts[4 * k4 + kk][cl];
            bh[kk] = *(const float4*)&ts[4 * k4 + kk][ch];
        }
#pragma unroll
        for (int ih = 0; ih < 2; ++ih) {
#pragma unroll
            for (int i = 0; i < 4; ++i) {
                const int rr = (ih ? 64 + 4 * ty : 4 * ty) + i;
                float4 av = *(const float4*)&ps[rr][4 * k4];
                const float a4[4] = {av.x, av.y, av.z, av.w};
                float* A = acc[4 * ih + i];
#pragma unroll
                for (int kk = 0; kk < 4; ++kk) {
                    const float* blp = (const float*)&bl[kk];
                    const float* bhp = (const float*)&bh[kk];
                    const float ak = a4[kk];
#pragma unroll
                    for (int j = 0; j < 4; ++j) {
                        A[j]     += ak * blp[j];
                        A[4 + j] += ak * bhp[j];
                    }
                }
            }
        }
    }

    float4 tlo = *(const float4*)&t2[cl];
    float4 thi = *(const float4*)&t2[ch];
    const float* tl = (const float*)&tlo;
    const float* th = (const float*)&thi;
#pragma unroll
    for (int ih = 0; ih < 2; ++ih) {
#pragma unroll
        for (int i = 0; i < 4; ++i) {
            const int rr = (ih ? 64 + 4 * ty : 4 * ty) + i;
            const float pa = p2[rr];
            float* A = acc[4 * ih + i];
            float4 o1, o2;
            o1.x = sqrtf(fmaxf(pa + tl[0] - 2.0f * A[0], 1e-12f));
            o1.y = sqrtf(fmaxf(pa + tl[1] - 2.0f * A[1], 1e-12f));
            o1.z = sqrtf(fmaxf(pa + tl[2] - 2.0f * A[2], 1e-12f));
            o1.w = sqrtf(fmaxf(pa + tl[3] - 2.0f * A[3], 1e-12f));
            o2.x = sqrtf(fmaxf(pa + th[0] - 2.0f * A[4], 1e-12f));
            o2.y = sqrtf(fmaxf(pa + th[1] - 2.0f * A[5], 1e-12f));
            o2.z = sqrtf(fmaxf(pa + th[2] - 2.0f * A[6], 1e-12f));
            o2.w = sqrtf(fmaxf(pa + th[3] - 2.0f * A[7], 1e-12f));
            float* Crow = C + (size_t)(row0 + rr) * T_LEN + col0;
            *(float4*)(Crow + cl) = o1;
            *(float4*)(Crow + ch) = o2;
        }
    }
}

// ---------------------------------------------------------------------------
// Kernel 2: Frechet DP — TWO ROWS PER STEP.
// Lane t at step s computes rows r0=2(s-t), r0+1 for cols [16t,16t+16).
// Steps: 575 (vs 1087) -> per-step overhead/stall amortized 2x; total
// dependent-med3 work unchanged. Cross-lane: shfl right-edge of both rows;
// diag of row r0 is lane t-1's row r0-1 edge = shfl(right1) delayed 1 step.
// Pipeline: PD=4 slots x 8 named float4, PLAIN C++ loads, consume-then-
// refill order -> compiler derives counted vmcnt itself (every inline-asm
// variant in rounds 1-4 ended in RA spill + conservative drain).
// Recurrence: max(c,min(min(up,left),diag)) == med3(left,c,max(c,min(up,diag)))
// (exact lattice identity; validated absmax=0 in rounds 3/4).
// ---------------------------------------------------------------------------
#define PD2 4

__global__ __launch_bounds__(64, 1) void dp_kernel(const float* __restrict__ cost,
                                                   float* __restrict__ out) {
    const int b = blockIdx.x;
    const int t = threadIdx.x;  // lane 0..63
    const float INF = __builtin_inff();
    const float* C = cost + (size_t)b * T_LEN * T_LEN + 16 * t;

    float prev[16];
#pragma unroll
    for (int j = 0; j < 16; ++j) prev[j] = INF;
    float right0 = INF;   // my row-r0 right edge (for neighbor's left0/diag1)
    float right1 = INF;   // my row-r1 right edge (for neighbor's left1)
    float diag2 = INF;    // shfl(right1) delayed one step -> diag of row r0

    // 4 slots x (2 rows x 4 float4), all individually named, plain loads.
    float4 s0a0, s0a1, s0a2, s0a3, s0b0, s0b1, s0b2, s0b3;
    float4 s1a0, s1a1, s1a2, s1a3, s1b0, s1b1, s1b2, s1b3;
    float4 s2a0, s2a1, s2a2, s2a3, s2b0, s2b1, s2b2, s2b3;
    float4 s3a0, s3a1, s3a2, s3a3, s3b0, s3b1, s3b2, s3b3;

#define DP2_FILL(D, A0, A1, A2, A3, B0, B1, B2, B3)                           \
    {                                                                         \
        int rn = 2 * ((D) - t);                                               \
        rn = rn < 0 ? 0 : (rn > T_LEN - 2 ? T_LEN - 2 : rn);                  \
        const float4* p0 = (const float4*)(C + (size_t)rn * T_LEN);           \
        const float4* p1 = (const float4*)(C + (size_t)(rn + 1) * T_LEN);     \
        A0 = p0[0]; A1 = p0[1]; A2 = p0[2]; A3 = p0[3];                       \
        B0 = p1[0]; B1 = p1[1]; B2 = p1[2]; B3 = p1[3];                       \
    }
    DP2_FILL(0, s0a0, s0a1, s0a2, s0a3, s0b0, s0b1, s0b2, s0b3)
    DP2_FILL(1, s1a0, s1a1, s1a2, s1a3, s1b0, s1b1, s1b2, s1b3)
    DP2_FILL(2, s2a0, s2a1, s2a2, s2a3, s2b0, s2b1, s2b2, s2b3)
    DP2_FILL(3, s3a0, s3a1, s3a2, s3a3, s3b0, s3b1, s3b2, s3b3)
#undef DP2_FILL

    const int S2 = (T_LEN / 2) + 63;            // 575 real steps
    const int NCH = (S2 + PD2 - 1) / PD2;       // 144 chunks -> 576 (tail guarded)
    int s = 0;

#define DP2_STEP(A0, A1, A2, A3, B0, B1, B2, B3)                              \
    {                                                                         \
        /* consume slot into locals (register renames), then refill slot */   \
        float4 a0 = A0, a1 = A1, a2 = A2, a3 = A3;                            \
        float4 b0 = B0, b1 = B1, b2 = B2, b3 = B3;                            \
        {                                                                     \
            int rn = 2 * (s + PD2 - t);                                       \
            rn = rn < 0 ? 0 : (rn > T_LEN - 2 ? T_LEN - 2 : rn);              \
            const float4* p0 = (const float4*)(C + (size_t)rn * T_LEN);       \
            const float4* p1 = (const float4*)(C + (size_t)(rn + 1) * T_LEN); \
            A0 = p0[0]; A1 = p0[1]; A2 = p0[2]; A3 = p0[3];                   \
            B0 = p1[0]; B1 = p1[1]; B2 = p1[2]; B3 = p1[3];                   \
        }                                                                     \
        const int r0 = 2 * (s - t);                                           \
        float inc0 = __shfl_up(right0, 1, 64);                                \
        float inc1 = __shfl_up(right1, 1, 64);                                \
        float left0 = inc0, diag0 = diag2;                                    \
        float left1 = inc1, diag1 = inc0;                                     \
        diag2 = inc1;                                                         \
        if (t == 0) {                                                         \
            left0 = (r0 == 0) ? -INF : INF;                                   \
            diag0 = INF; left1 = INF; diag1 = INF;                            \
        }                                                                     \
        if (r0 >= 0 && r0 < T_LEN) {                                          \
            float ca[16] = {a0.x, a0.y, a0.z, a0.w, a1.x, a1.y, a1.z, a1.w,   \
                            a2.x, a2.y, a2.z, a2.w, a3.x, a3.y, a3.z, a3.w};  \
            float cb[16] = {b0.x, b0.y, b0.z, b0.w, b1.x, b1.y, b1.z, b1.w,   \
                            b2.x, b2.y, b2.z, b2.w, b3.x, b3.y, b3.z, b3.w};  \
            float g[16];                                                      \
            g[0] = fmaxf(ca[0], fminf(prev[0], diag0));                       \
            _Pragma("unroll")                                                 \
            for (int j = 1; j < 16; ++j)                                      \
                g[j] = fmaxf(ca[j], fminf(prev[j], prev[j - 1]));             \
            float v = left0;                                                  \
            _Pragma("unroll")                                                 \
            for (int j = 0; j < 16; ++j) {                                    \
                v = __builtin_amdgcn_fmed3f(v, ca[j], g[j]);                  \
                prev[j] = v;                                                  \
            }                                                                 \
            right0 = v;                                                       \
            float h[16];                                                      \
            h[0] = fmaxf(cb[0], fminf(prev[0], diag1));                       \
            _Pragma("unroll")                                                 \
            for (int j = 1; j < 16; ++j)                                      \
                h[j] = fmaxf(cb[j], fminf(prev[j], prev[j - 1]));             \
            float w = left1;                                                  \
            _Pragma("unroll")                                                 \
            for (int j = 0; j < 16; ++j) {                                    \
                w = __builtin_amdgcn_fmed3f(w, cb[j], h[j]);                  \
                prev[j] = w;                                                  \
            }                                                                 \
            right1 = w;                                                       \
        }                                                                     \
        ++s;                                                                  \
    }

    for (int chunk = 0; chunk < NCH; ++chunk) {
        DP2_STEP(s0a0, s0a1, s0a2, s0a3, s0b0, s0b1, s0b2, s0b3)
        DP2_STEP(s1a0, s1a1, s1a2, s1a3, s1b0, s1b1, s1b2, s1b3)
        DP2_STEP(s2a0, s2a1, s2a2, s2a3, s2b0, s2b1, s2b2, s2b3)
        DP2_STEP(s3a0, s3a1, s3a2, s3a3, s3b0, s3b1, s3b2, s3b3)
    }
#undef DP2_STEP

    if (t == 63) atomicAdd(out, prev[15] * (1.0f / (float)BATCH));
}

// ---------------------------------------------------------------------------
// Fallback: fused DP computing distances on the fly (only if ws can't hold
// one 4 MB cost matrix). Unchanged.
// ---------------------------------------------------------------------------
__global__ __launch_bounds__(64) void dp_fused_kernel(const float* __restrict__ pred,
                                                      const float* __restrict__ targ,
                                                      float* __restrict__ out) {
    const int b = blockIdx.x;
    const int t = threadIdx.x;
    const float INF = __builtin_inff();
    const float* P = pred + (size_t)b * T_LEN * D_DIM;
    const float* T = targ + (size_t)b * T_LEN * D_DIM + (size_t)(16 * t) * D_DIM;

    float prev[16];
#pragma unroll
    for (int j = 0; j < 16; ++j) prev[j] = INF;
    float right_out = INF;
    float diag_feed = INF;

    for (int s = 0; s < T_LEN + 63; s++) {
        int r = s - t;
        float inc = __shfl_up(right_out, 1, 64);
        float left = inc, diag = diag_feed;
        diag_feed = inc;
        if (t == 0) { left = (r == 0) ? -INF : INF; diag = INF; }
        if (r >= 0 && r < T_LEN) {
            float4 pr[16];
            const float4* pp = (const float4*)(P + (size_t)r * D_DIM);
#pragma unroll
            for (int q = 0; q < 16; q++) pr[q] = pp[q];
#pragma unroll
            for (int j = 0; j < 16; j++) {
                const float4* tp = (const float4*)(T + (size_t)j * D_DIM);
                float acc = 0.0f;
#pragma unroll
                for (int q = 0; q < 16; q++) {
                    float4 tv = tp[q];
                    float dx = pr[q].x - tv.x; acc += dx * dx;
                    float dy = pr[q].y - tv.y; acc += dy * dy;
                    float dz = pr[q].z - tv.z; acc += dz * dz;
                    float dw = pr[q].w - tv.w; acc += dw * dw;
                }
                float c = sqrtf(fmaxf(acc, 1e-12f));
                float up = prev[j];
                float v = fmaxf(c, fminf(fminf(up, diag), left));
                diag = up; left = v; prev[j] = v;
            }
            right_out = left;
        }
    }
    if (t == 63) atomicAdd(out, prev[15] * (1.0f / (float)BATCH));
}

extern "C" void kernel_launch(void* const* d_in, const int* in_sizes, int n_in,
                              void* d_out, int out_size, void* d_ws, size_t ws_size,
                              hipStream_t stream) {
    const float* pred = (const float*)d_in[0];
    const float* targ = (const float*)d_in[1];
    float* out = (float*)d_out;

    hipMemsetAsync(out, 0, sizeof(float) * out_size, stream);

    const size_t per_batch = (size_t)T_LEN * T_LEN * sizeof(float);  // 4 MB
    int bpg = (int)(ws_size / per_batch);
    if (bpg > BATCH) bpg = BATCH;

    if (bpg >= 1) {
        float* cost = (float*)d_ws;
        for (int g0 = 0; g0 < BATCH; g0 += bpg) {
            int gb = (BATCH - g0) < bpg ? (BATCH - g0) : bpg;
            dim3 grid(T_LEN / BN, T_LEN / BM, gb);
            cost_kernel<<<grid, 256, 0, stream>>>(pred + (size_t)g0 * T_LEN * D_DIM,
                                                  targ + (size_t)g0 * T_LEN * D_DIM,
                                                  cost);
            dp_kernel<<<gb, 64, 0, stream>>>(cost, out);
        }
    } else {
        dp_fused_kernel<<<BATCH, 64, 0, stream>>>(pred, targ, out);
    }
}